// Round 6
// baseline (184.636 us; speedup 1.0000x reference)
//
#include <hip/hip_runtime.h>
#include <math.h>

constexpr int B_ = 128;
constexpr int N_ = 512;
constexpr int K_ = 510;     // number of diagonals = N-2
constexpr int SPLIT = 16;   // blocks per batch; block s owns row-chunks {s, 31-s}

// Kernel 1: thread t owns diagonals k_a = t (rows p < 511-t) and
// k_b = 511-t (rows p < t), register accumulation (unchanged from R4).
// NEW: block s processes two CONTIGUOUS 16-row chunks, rows [16s,16s+16)
// and [496-16s, 512-16s) -- consecutive iterations are 2 KB apart, so the
// block streams a contiguous ~32-64 KB region instead of jumping 32 KB per
// row (R5 pattern: scattered 256 B bursts -> ~2 TB/s effective). Chunk
// pairing keeps per-block work exactly constant (8176 elements).
// Specialization: low chunk (p<=255): a-loads unconditional (p < la always);
// high chunk (p>=256): b-stream impossible (p >= 256 > t), loop dropped.
__global__ __launch_bounds__(256) void diag_partial_kernel(
    const float* __restrict__ in, float* __restrict__ ws) {
  const int b = blockIdx.x / SPLIT;
  const int s = blockIdx.x % SPLIT;
  const int t = threadIdx.x;            // t in [0,256)
  const float* base = in + (size_t)b * N_ * N_;
  const int la = (N_ - 1) - t;          // a-stream: p < la
  const int lb = t;                     // b-stream: p < lb
  float Sa0 = 0.f, Qa0 = 0.f, Sa1 = 0.f, Qa1 = 0.f;
  float Sb0 = 0.f, Qb0 = 0.f, Sb1 = 0.f, Qb1 = 0.f;

  // --- low chunk: rows [16s, 16s+16), p <= 255 < 256 <= la ---
  {
    const int r0 = 16 * s;
    const float* pa = base + (size_t)r0 * (N_ + 1) + 1 + t;
    const float* pb = base + (size_t)r0 * (N_ + 1) + (N_ - t);
#pragma unroll
    for (int i = 0; i < 16; i += 2) {
      const int p0 = r0 + i;
      const int p1 = r0 + i + 1;
      float a0 = pa[0];
      float a1 = pa[N_ + 1];
      float b0 = (p0 < lb) ? pb[0] : 0.f;
      float b1 = (p1 < lb) ? pb[N_ + 1] : 0.f;
      Sa0 += a0; Qa0 = fmaf(a0, a0, Qa0);
      Sa1 += a1; Qa1 = fmaf(a1, a1, Qa1);
      Sb0 += b0; Qb0 = fmaf(b0, b0, Qb0);
      Sb1 += b1; Qb1 = fmaf(b1, b1, Qb1);
      pa += 2 * (N_ + 1);
      pb += 2 * (N_ + 1);
    }
  }
  // --- high chunk: rows [496-16s, 512-16s), p >= 256 > lb: a only ---
  {
    const int r0 = (N_ - 16) - 16 * s;
    const float* pa = base + (size_t)r0 * (N_ + 1) + 1 + t;
#pragma unroll
    for (int i = 0; i < 16; i += 2) {
      const int p0 = r0 + i;
      const int p1 = r0 + i + 1;
      float a0 = (p0 < la) ? pa[0] : 0.f;
      float a1 = (p1 < la) ? pa[N_ + 1] : 0.f;
      Sa0 += a0; Qa0 = fmaf(a0, a0, Qa0);
      Sa1 += a1; Qa1 = fmaf(a1, a1, Qa1);
      pa += 2 * (N_ + 1);
    }
  }

  float* w = ws + (size_t)blockIdx.x * (2 * N_);  // blockIdx.x == b*SPLIT+s
  // thread t writes k=t and k=511-t (disjoint: [0,256) vs [256,512))
  w[t] = Sa0 + Sa1;
  w[t + N_] = Qa0 + Qa1;
  w[(N_ - 1) - t] = Sb0 + Sb1;
  w[(N_ - 1) - t + N_] = Qb0 + Qb1;
}

// Kernel 2: combine partials (fully-unrolled constant-trip loop -> 32
// independent loads in flight), compute scaled = sqrt(var)*len/5 per k,
// reduce mean over k, write both tuple outputs.
__global__ __launch_bounds__(512) void finalize_kernel(
    const float* __restrict__ ws, float* __restrict__ out) {
  __shared__ float red[8];
  const int b = blockIdx.x;
  const int t = threadIdx.x;
  float Ssum = 0.0f, Qsum = 0.0f;
#pragma unroll
  for (int s = 0; s < SPLIT; ++s) {
    const float* w = ws + (size_t)(b * SPLIT + s) * (2 * N_);
    Ssum += w[t];
    Qsum += w[t + N_];
  }
  float scaled = 0.0f;
  if (t < K_) {
    float len = (float)(N_ - 1 - t);
    float mean = Ssum / len;
    float var = (Qsum - Ssum * mean) / (len - 1.0f);
    var = fmaxf(var, 0.0f);        // guard tiny negative from rounding
    scaled = sqrtf(var) * len * 0.2f;
  }
  // wave-64 reduction
  for (int off = 32; off > 0; off >>= 1)
    scaled += __shfl_down(scaled, off, 64);
  const int wid = t >> 6;
  if ((t & 63) == 0) red[wid] = scaled;
  __syncthreads();
  if (t == 0) {
    float tot = 0.0f;
    for (int i = 0; i < 8; ++i) tot += red[i];
    float loss = tot / (float)K_;
    out[b] = loss;        // output 0: loss
    out[B_ + b] = loss;   // output 1: stop_gradient(loss) == loss
  }
}

extern "C" void kernel_launch(void* const* d_in, const int* in_sizes, int n_in,
                              void* d_out, int out_size, void* d_ws, size_t ws_size,
                              hipStream_t stream) {
  const float* in = (const float*)d_in[0];
  float* out = (float*)d_out;
  float* ws = (float*)d_ws;
  // 2048 blocks of 256 threads; ws use: 8 MB.
  diag_partial_kernel<<<B_ * SPLIT, 256, 0, stream>>>(in, ws);
  finalize_kernel<<<B_, 512, 0, stream>>>(ws, out);
}